// Round 12
// baseline (963.555 us; speedup 1.0000x reference)
//
#include <hip/hip_runtime.h>
#include <hip/hip_bf16.h>

#define SEQ   110
#define HALFS 55
#define EMB   102
#define HEAD  192

typedef short bf16x8 __attribute__((ext_vector_type(8)));
typedef float f32x4  __attribute__((ext_vector_type(4)));

#define XS    104               // tile row stride (shorts), 13 granules (odd)
#define XTILE (64 * XS)         // 6656 shorts per tile
#define PS    72                // P_lds row stride (shorts), 9 granules (odd)
#define MTS   128               // Mt row stride (shorts)
#define MTROWS 112
#define MT_SHORTS (MTROWS * MTS)   // 14336
#define WES   128               // WvT e-stride

__device__ __forceinline__ short f2bf(float f) {
    unsigned u = __float_as_uint(f);
    unsigned r = u + 0x7fffu + ((u >> 16) & 1u);   // RNE
    return (short)(r >> 16);
}
__device__ __forceinline__ unsigned pk2(float a, float b) {
    return ((unsigned)(unsigned short)f2bf(b) << 16) | (unsigned short)f2bf(a);
}

// ws layout: [ Mt : 112x128 bf16 ][ WvT : 192x128 bf16 ]
// Mt[i][j] = scale * sum_h Wq[j][h] * Wk[i][h]; WvT[h][e] = Wv[e][h]; zero-padded.
__global__ void prep(const float* __restrict__ Wq, const float* __restrict__ Wk,
                     const float* __restrict__ Wv, short* __restrict__ ws) {
    int flat = blockIdx.x * 256 + threadIdx.x;
    if (flat < MT_SHORTS) {
        int i = flat >> 7, j = flat & 127;
        float v = 0.0f;
        if (i < EMB && j < EMB) {
            const float4* q4 = (const float4*)(Wq + j * HEAD);
            const float4* k4 = (const float4*)(Wk + i * HEAD);
            float s = 0.0f;
            #pragma unroll 4
            for (int h4 = 0; h4 < HEAD / 4; ++h4) {
                float4 a = q4[h4], b = k4[h4];
                s += a.x * b.x + a.y * b.y + a.z * b.z + a.w * b.w;
            }
            v = s * 0.07216878364870322f;   // 1/sqrt(192)
        }
        ws[flat] = f2bf(v);
    } else if (flat < MT_SHORTS + HEAD * WES) {
        int idx = flat - MT_SHORTS;
        int h = idx >> 7, e = idx & 127;
        float v = (e < EMB) ? Wv[e * HEAD + h] : 0.0f;
        ws[flat] = f2bf(v);
    }
}

// 512 persistent blocks x 512 threads (16 batches each). Waves 0-3 = half 0,
// waves 4-7 = half 1, processed CONCURRENTLY. LDS 71.7KB (x0,x1,y0,y1 + 2x P)
// -> 2 blocks/CU = 4 waves/SIMD. 4 barriers/batch. Math identical to R11.
__global__ __launch_bounds__(512, 4)
void attn_head(const float* __restrict__ x, const short* __restrict__ ws,
               float* __restrict__ out, int B) {
    const int tid  = threadIdx.x;
    const int w8   = tid >> 6;        // 0..7
    const int h    = w8 >> 2;         // half group
    const int w4   = w8 & 3;          // wave within group
    const int lane = tid & 63;
    const int g    = lane >> 4;
    const int r    = lane & 15;

    __shared__ __attribute__((aligned(16))) short u[4 * XTILE];       // 53248 B: x0,x1,y0,y1
    __shared__ __attribute__((aligned(16))) short P_lds[2][64 * PS];  // 18432 B

    short* xh = u + h * XTILE;          // own-half x (source of queries' y)
    short* xo = u + (h ^ 1) * XTILE;    // other-half x (keys/values)
    short* yh = u + (2 + h) * XTILE;    // own-half y
    short* Ph = P_lds[h];

    const short* Mt  = ws;
    const short* WvT = ws + MT_SHORTS;

    bf16x8 wvf[3][4];
    #pragma unroll
    for (int mi = 0; mi < 3; ++mi) {
        const int hrow = 16 * (w4 + 4 * mi) + r;
        #pragma unroll
        for (int kk = 0; kk < 4; ++kk)
            wvf[mi][kk] = *(const bf16x8*)(WvT + hrow * WES + 32 * kk + 8 * g);
    }

    // one-time pad zeroing of x0/x1 (rows 55..63; cols 102/103 rows 0..54)
    {
        unsigned long long* z = (unsigned long long*)u;
        if (tid < 468) z[(tid < 234 ? 1430 : 2860) + tid] = 0ull;
        if (tid < 110)
            *(unsigned*)(u + (tid & 1) * XTILE + (tid >> 1) * XS + 102) = 0u;
    }

    unsigned xv0[6], xv1[6];
    auto loadx = [&](int batch) {
        const float4* xb4 = (const float4*)(x + (size_t)batch * (SEQ * EMB));
        #pragma unroll
        for (int it = 0; it < 6; ++it) {
            int i4 = tid + it * 512;
            if (i4 < 2805) { float4 v = xb4[i4]; xv0[it] = pk2(v.x, v.y); xv1[it] = pk2(v.z, v.w); }
        }
    };
    auto stagex = [&]() {
        #pragma unroll
        for (int it = 0; it < 6; ++it) {
            int i4 = tid + it * 512;
            if (i4 < 2805) {
                int fc  = i4 * 4;
                int row = (int)(((unsigned long long)fc * 41121ull) >> 22);  // /102
                int e   = fc - row * EMB;
                int tile = row >= HALFS;
                int lr   = row - HALFS * tile;
                int ba   = tile * XTILE + lr * XS + e;
                if (e == 100) {
                    int rowb  = row + 1;
                    int tileb = rowb >= HALFS;
                    int lrb   = rowb - HALFS * tileb;
                    *(unsigned*)(u + ba) = xv0[it];
                    *(unsigned*)(u + tileb * XTILE + lrb * XS) = xv1[it];
                } else {
                    uint2 t2; t2.x = xv0[it]; t2.y = xv1[it];
                    *(uint2*)(u + ba) = t2;
                }
            }
        }
    };

    loadx(blockIdx.x);
    const int stride = (int)gridDim.x;

    bf16x8 ax[4][4];
    bf16x8 zz = {};

    #pragma unroll 1
    for (int p = blockIdx.x; p < B; p += stride) {
        stagex();
        __syncthreads();                 // bar1: x staged

        // G A-frags (transient)
        bf16x8 am[2][4];
        #pragma unroll
        for (int mi2 = 0; mi2 < 2; ++mi2) {
            const int mt = w4 + 4 * mi2;
            #pragma unroll
            for (int kk = 0; kk < 4; ++kk)
                am[mi2][kk] = (mt < 7) ? *(const bf16x8*)(Mt + (16 * mt + r) * MTS + 32 * kk + 8 * g) : zz;
        }

        // y_h = x_h @ G -> yh (group h computes its own half's y)
        #pragma unroll
        for (int stl = 0; stl < 4; ++stl) {
            const short* xb = xh + (16 * stl + r) * XS;
            bf16x8 bx[4];
            #pragma unroll
            for (int kk = 0; kk < 3; ++kk) bx[kk] = *(const bf16x8*)(xb + 32 * kk + 8 * g);
            bx[3] = zz;
            if (g == 0) bx[3] = *(const bf16x8*)(xb + 96);
            #pragma unroll
            for (int mi2 = 0; mi2 < 2; ++mi2) {
                const int mt = w4 + 4 * mi2;
                if (mt < 7) {
                    f32x4 acc = {0.f, 0.f, 0.f, 0.f};
                    #pragma unroll
                    for (int kk = 0; kk < 4; ++kk)
                        acc = __builtin_amdgcn_mfma_f32_16x16x32_bf16(am[mi2][kk], bx[kk], acc, 0, 0, 0);
                    if (mt < 6 || g < 2) {
                        uint2 t2; t2.x = pk2(acc[0], acc[1]); t2.y = pk2(acc[2], acc[3]);
                        *(uint2*)(yh + (16 * stl + r) * XS + 16 * mt + 4 * g) = t2;
                    }
                }
            }
        }

        // hoist ax = other-half x (keys/values)
        #pragma unroll
        for (int mt = 0; mt < 4; ++mt) {
            const short* xb = xo + (16 * mt + r) * XS;
            #pragma unroll
            for (int kk = 0; kk < 3; ++kk) ax[mt][kk] = *(const bf16x8*)(xb + 32 * kk + 8 * g);
            ax[mt][3] = zz;
            if (g == 0) ax[mt][3] = *(const bf16x8*)(xb + 96);
        }

        // v-GEMM (regs only) + v-exchange
        unsigned vpk[4][3][2];
        #pragma unroll
        for (int st = 0; st < 4; ++st) {
            #pragma unroll
            for (int mi = 0; mi < 3; ++mi) {
                f32x4 acc = {0.f, 0.f, 0.f, 0.f};
                #pragma unroll
                for (int kk = 0; kk < 4; ++kk)
                    acc = __builtin_amdgcn_mfma_f32_16x16x32_bf16(ax[st][kk], wvf[mi][kk], acc, 0, 0, 0);
                vpk[st][mi][0] = pk2(acc[0], acc[1]);
                vpk[st][mi][1] = pk2(acc[2], acc[3]);
            }
        }
        const int src0 = ((g & 1) << 5) + r;
        const int src1 = src0 + 16;
        const bool hi  = (g >> 1) != 0;
        bf16x8 va[3][2];
        #pragma unroll
        for (int mi = 0; mi < 3; ++mi) {
            unsigned e00 = (unsigned)__shfl((int)vpk[0][mi][0], src0), e01 = (unsigned)__shfl((int)vpk[0][mi][1], src0);
            unsigned e02 = (unsigned)__shfl((int)vpk[0][mi][0], src1), e03 = (unsigned)__shfl((int)vpk[0][mi][1], src1);
            unsigned f00 = (unsigned)__shfl((int)vpk[1][mi][0], src0), f01 = (unsigned)__shfl((int)vpk[1][mi][1], src0);
            unsigned f02 = (unsigned)__shfl((int)vpk[1][mi][0], src1), f03 = (unsigned)__shfl((int)vpk[1][mi][1], src1);
            uint4 u0;
            u0.x = hi ? f00 : e00; u0.y = hi ? f01 : e01; u0.z = hi ? f02 : e02; u0.w = hi ? f03 : e03;
            unsigned e10 = (unsigned)__shfl((int)vpk[2][mi][0], src0), e11 = (unsigned)__shfl((int)vpk[2][mi][1], src0);
            unsigned e12 = (unsigned)__shfl((int)vpk[2][mi][0], src1), e13 = (unsigned)__shfl((int)vpk[2][mi][1], src1);
            unsigned f10 = (unsigned)__shfl((int)vpk[3][mi][0], src0), f11 = (unsigned)__shfl((int)vpk[3][mi][1], src0);
            unsigned f12 = (unsigned)__shfl((int)vpk[3][mi][0], src1), f13 = (unsigned)__shfl((int)vpk[3][mi][1], src1);
            uint4 u1;
            u1.x = hi ? f10 : e10; u1.y = hi ? f11 : e11; u1.z = hi ? f12 : e12; u1.w = hi ? f13 : e13;
            __builtin_memcpy(&va[mi][0], &u0, 16);
            __builtin_memcpy(&va[mi][1], &u1, 16);
        }

        __syncthreads();                 // bar2: y visible (x reads all done too)

        if (p + stride < B) loadx(p + stride);   // prefetch under compute

        // scores + softmax for this wave's query tile c = w4 (own half)
        {
            const short* yb = yh + (16 * w4 + r) * XS;
            bf16x8 by[4];
            #pragma unroll
            for (int kk = 0; kk < 3; ++kk) by[kk] = *(const bf16x8*)(yb + 32 * kk + 8 * g);
            by[3] = zz;
            if (g == 0) by[3] = *(const bf16x8*)(yb + 96);

            float sc[4][4];
            #pragma unroll
            for (int mt = 0; mt < 4; ++mt) {
                f32x4 acc = {0.f, 0.f, 0.f, 0.f};
                #pragma unroll
                for (int kk = 0; kk < 4; ++kk)
                    acc = __builtin_amdgcn_mfma_f32_16x16x32_bf16(ax[mt][kk], by[kk], acc, 0, 0, 0);
                #pragma unroll
                for (int j = 0; j < 4; ++j) sc[mt][j] = acc[j];
            }
            #pragma unroll
            for (int j = 0; j < 4; ++j)
                if (48 + 4 * g + j >= HALFS) sc[3][j] = -1e30f;

            float mx = -1e30f;
            #pragma unroll
            for (int mt = 0; mt < 4; ++mt) {
                #pragma unroll
                for (int j = 0; j < 4; ++j) mx = fmaxf(mx, sc[mt][j]);
            }
            mx = fmaxf(mx, __shfl_xor(mx, 16));
            mx = fmaxf(mx, __shfl_xor(mx, 32));
            float pr[4][4];
            float sum = 0.f;
            #pragma unroll
            for (int mt = 0; mt < 4; ++mt) {
                #pragma unroll
                for (int j = 0; j < 4; ++j) { pr[mt][j] = __expf(sc[mt][j] - mx); sum += pr[mt][j]; }
            }
            sum += __shfl_xor(sum, 16);
            sum += __shfl_xor(sum, 32);
            float rs = 1.0f / sum;

            #pragma unroll
            for (int mt = 0; mt < 4; ++mt) {
                uint2 t2;
                t2.x = pk2(pr[mt][0] * rs, pr[mt][1] * rs);
                t2.y = pk2(pr[mt][2] * rs, pr[mt][3] * rs);
                *(uint2*)(Ph + (16 * w4 + r) * PS + 16 * mt + 4 * g) = t2;
            }
        }
        __syncthreads();                 // P-bar: all P rows of both groups visible

        // PV per c, stores to this group's output half
        const size_t obase = (size_t)p * (SEQ * HEAD) + (size_t)(h * HALFS) * HEAD;
        #pragma unroll
        for (int c = 0; c < 4; ++c) {
            const short* pb = Ph + (16 * c + r) * PS + 8 * g;
            bf16x8 bp0 = *(const bf16x8*)(pb);
            bf16x8 bp1 = *(const bf16x8*)(pb + 32);
            const int srow  = 16 * c + r;
            const bool valid = srow < HALFS;
            float* orow = out + obase + (size_t)srow * HEAD;
            #pragma unroll
            for (int mi = 0; mi < 3; ++mi) {
                f32x4 acc = {0.f, 0.f, 0.f, 0.f};
                acc = __builtin_amdgcn_mfma_f32_16x16x32_bf16(va[mi][0], bp0, acc, 0, 0, 0);
                acc = __builtin_amdgcn_mfma_f32_16x16x32_bf16(va[mi][1], bp1, acc, 0, 0, 0);
                if (valid) {
                    float4 st4; st4.x = acc[0]; st4.y = acc[1]; st4.z = acc[2]; st4.w = acc[3];
                    *(float4*)(orow + 16 * (w4 + 4 * mi) + 4 * g) = st4;
                }
            }
        }
        __syncthreads();                 // bar-end: y/P reads done before next stage
    }
}

extern "C" void kernel_launch(void* const* d_in, const int* in_sizes, int n_in,
                              void* d_out, int out_size, void* d_ws, size_t ws_size,
                              hipStream_t stream) {
    const float* x  = (const float*)d_in[0];
    const float* Wq = (const float*)d_in[1];
    const float* Wk = (const float*)d_in[2];
    const float* Wv = (const float*)d_in[3];
    short* ws = (short*)d_ws;                       // needs (14336+24576)*2 = 77824 B
    int B = in_sizes[0] / (SEQ * EMB);              // 8192
    int prep_elems = MT_SHORTS + HEAD * WES;
    prep<<<(prep_elems + 255) / 256, 256, 0, stream>>>(Wq, Wk, Wv, ws);
    attn_head<<<512, 512, 0, stream>>>(x, ws, (float*)d_out, B);
}

// Round 13
// 303.082 us; speedup vs baseline: 3.1792x; 3.1792x over previous
//
#include <hip/hip_runtime.h>
#include <hip/hip_bf16.h>

#define SEQ   110
#define HALFS 55
#define EMB   102
#define HEAD  192

typedef short bf16x8 __attribute__((ext_vector_type(8)));
typedef float f32x4  __attribute__((ext_vector_type(4)));

#define XS    104               // tile row stride (shorts), 13 granules (odd)
#define XTILE (64 * XS)         // 6656 shorts per tile
#define PS    72                // P_lds row stride (shorts), 9 granules (odd)
#define MTS   128               // Mt row stride (shorts)
#define MTROWS 112
#define MT_SHORTS (MTROWS * MTS)   // 14336
#define WES   128               // WvT e-stride

__device__ __forceinline__ short f2bf(float f) {
    unsigned u = __float_as_uint(f);
    unsigned r = u + 0x7fffu + ((u >> 16) & 1u);   // RNE
    return (short)(r >> 16);
}
__device__ __forceinline__ unsigned pk2(float a, float b) {
    return ((unsigned)(unsigned short)f2bf(b) << 16) | (unsigned short)f2bf(a);
}

// ws layout: [ Mt : 112x128 bf16 ][ WvT : 192x128 bf16 ]
// Mt[i][j] = scale * sum_h Wq[j][h] * Wk[i][h]; WvT[h][e] = Wv[e][h]; zero-padded.
__global__ void prep(const float* __restrict__ Wq, const float* __restrict__ Wk,
                     const float* __restrict__ Wv, short* __restrict__ ws) {
    int flat = blockIdx.x * 256 + threadIdx.x;
    if (flat < MT_SHORTS) {
        int i = flat >> 7, j = flat & 127;
        float v = 0.0f;
        if (i < EMB && j < EMB) {
            const float4* q4 = (const float4*)(Wq + j * HEAD);
            const float4* k4 = (const float4*)(Wk + i * HEAD);
            float s = 0.0f;
            #pragma unroll 4
            for (int h4 = 0; h4 < HEAD / 4; ++h4) {
                float4 a = q4[h4], b = k4[h4];
                s += a.x * b.x + a.y * b.y + a.z * b.z + a.w * b.w;
            }
            v = s * 0.07216878364870322f;   // 1/sqrt(192)
        }
        ws[flat] = f2bf(v);
    } else if (flat < MT_SHORTS + HEAD * WES) {
        int idx = flat - MT_SHORTS;
        int h = idx >> 7, e = idx & 127;
        float v = (e < EMB) ? Wv[e * HEAD + h] : 0.0f;
        ws[flat] = f2bf(v);
    }
}

// 512 persistent blocks x 512 threads (16 batches each). Waves 0-3 = half 0,
// waves 4-7 = half 1, CONCURRENT. LDS 71.7KB. 4 barriers/batch.
// R12 spilled because __launch_bounds__(512,4) capped arch-VGPRs at 64 (needed
// ~128 -> 900MB scratch). (512,2) gives the 128-reg budget R11 is proven to fit.
__global__ __launch_bounds__(512, 2)
void attn_head(const float* __restrict__ x, const short* __restrict__ ws,
               float* __restrict__ out, int B) {
    const int tid  = threadIdx.x;
    const int w8   = tid >> 6;        // 0..7
    const int h    = w8 >> 2;         // half group
    const int w4   = w8 & 3;          // wave within group
    const int lane = tid & 63;
    const int g    = lane >> 4;
    const int r    = lane & 15;

    __shared__ __attribute__((aligned(16))) short u[4 * XTILE];       // 53248 B: x0,x1,y0,y1
    __shared__ __attribute__((aligned(16))) short P_lds[2][64 * PS];  // 18432 B

    short* xh = u + h * XTILE;          // own-half x
    short* xo = u + (h ^ 1) * XTILE;    // other-half x (keys/values)
    short* yh = u + (2 + h) * XTILE;    // own-half y
    short* Ph = P_lds[h];

    const short* Mt  = ws;
    const short* WvT = ws + MT_SHORTS;

    bf16x8 wvf[3][4];
    #pragma unroll
    for (int mi = 0; mi < 3; ++mi) {
        const int hrow = 16 * (w4 + 4 * mi) + r;
        #pragma unroll
        for (int kk = 0; kk < 4; ++kk)
            wvf[mi][kk] = *(const bf16x8*)(WvT + hrow * WES + 32 * kk + 8 * g);
    }

    // one-time pad zeroing of x0/x1 (rows 55..63; cols 102/103 rows 0..54)
    {
        unsigned long long* z = (unsigned long long*)u;
        if (tid < 468) z[(tid < 234 ? 1430 : 2860) + tid] = 0ull;
        if (tid < 110)
            *(unsigned*)(u + (tid & 1) * XTILE + (tid >> 1) * XS + 102) = 0u;
    }

    unsigned xv0[6], xv1[6];
    auto loadx = [&](int batch) {
        const float4* xb4 = (const float4*)(x + (size_t)batch * (SEQ * EMB));
        #pragma unroll
        for (int it = 0; it < 6; ++it) {
            int i4 = tid + it * 512;
            if (i4 < 2805) { float4 v = xb4[i4]; xv0[it] = pk2(v.x, v.y); xv1[it] = pk2(v.z, v.w); }
        }
    };
    auto stagex = [&]() {
        #pragma unroll
        for (int it = 0; it < 6; ++it) {
            int i4 = tid + it * 512;
            if (i4 < 2805) {
                int fc  = i4 * 4;
                int row = (int)(((unsigned long long)fc * 41121ull) >> 22);  // /102
                int e   = fc - row * EMB;
                int tile = row >= HALFS;
                int lr   = row - HALFS * tile;
                int ba   = tile * XTILE + lr * XS + e;
                if (e == 100) {
                    int rowb  = row + 1;
                    int tileb = rowb >= HALFS;
                    int lrb   = rowb - HALFS * tileb;
                    *(unsigned*)(u + ba) = xv0[it];
                    *(unsigned*)(u + tileb * XTILE + lrb * XS) = xv1[it];
                } else {
                    uint2 t2; t2.x = xv0[it]; t2.y = xv1[it];
                    *(uint2*)(u + ba) = t2;
                }
            }
        }
    };

    loadx(blockIdx.x);
    const int stride = (int)gridDim.x;

    bf16x8 ax[4][4];
    bf16x8 zz = {};

    #pragma unroll 1
    for (int p = blockIdx.x; p < B; p += stride) {
        stagex();
        __syncthreads();                 // bar1: x staged

        // G A-frags (transient)
        bf16x8 am[2][4];
        #pragma unroll
        for (int mi2 = 0; mi2 < 2; ++mi2) {
            const int mt = w4 + 4 * mi2;
            #pragma unroll
            for (int kk = 0; kk < 4; ++kk)
                am[mi2][kk] = (mt < 7) ? *(const bf16x8*)(Mt + (16 * mt + r) * MTS + 32 * kk + 8 * g) : zz;
        }

        // y_h = x_h @ G -> yh
        #pragma unroll
        for (int stl = 0; stl < 4; ++stl) {
            const short* xb = xh + (16 * stl + r) * XS;
            bf16x8 bx[4];
            #pragma unroll
            for (int kk = 0; kk < 3; ++kk) bx[kk] = *(const bf16x8*)(xb + 32 * kk + 8 * g);
            bx[3] = zz;
            if (g == 0) bx[3] = *(const bf16x8*)(xb + 96);
            #pragma unroll
            for (int mi2 = 0; mi2 < 2; ++mi2) {
                const int mt = w4 + 4 * mi2;
                if (mt < 7) {
                    f32x4 acc = {0.f, 0.f, 0.f, 0.f};
                    #pragma unroll
                    for (int kk = 0; kk < 4; ++kk)
                        acc = __builtin_amdgcn_mfma_f32_16x16x32_bf16(am[mi2][kk], bx[kk], acc, 0, 0, 0);
                    if (mt < 6 || g < 2) {
                        uint2 t2; t2.x = pk2(acc[0], acc[1]); t2.y = pk2(acc[2], acc[3]);
                        *(uint2*)(yh + (16 * stl + r) * XS + 16 * mt + 4 * g) = t2;
                    }
                }
            }
        }

        // hoist ax = other-half x (keys/values)
        #pragma unroll
        for (int mt = 0; mt < 4; ++mt) {
            const short* xb = xo + (16 * mt + r) * XS;
            #pragma unroll
            for (int kk = 0; kk < 3; ++kk) ax[mt][kk] = *(const bf16x8*)(xb + 32 * kk + 8 * g);
            ax[mt][3] = zz;
            if (g == 0) ax[mt][3] = *(const bf16x8*)(xb + 96);
        }

        // v-GEMM (regs only) + v-exchange
        unsigned vpk[4][3][2];
        #pragma unroll
        for (int st = 0; st < 4; ++st) {
            #pragma unroll
            for (int mi = 0; mi < 3; ++mi) {
                f32x4 acc = {0.f, 0.f, 0.f, 0.f};
                #pragma unroll
                for (int kk = 0; kk < 4; ++kk)
                    acc = __builtin_amdgcn_mfma_f32_16x16x32_bf16(ax[st][kk], wvf[mi][kk], acc, 0, 0, 0);
                vpk[st][mi][0] = pk2(acc[0], acc[1]);
                vpk[st][mi][1] = pk2(acc[2], acc[3]);
            }
        }
        const int src0 = ((g & 1) << 5) + r;
        const int src1 = src0 + 16;
        const bool hi  = (g >> 1) != 0;
        bf16x8 va[3][2];
        #pragma unroll
        for (int mi = 0; mi < 3; ++mi) {
            unsigned e00 = (unsigned)__shfl((int)vpk[0][mi][0], src0), e01 = (unsigned)__shfl((int)vpk[0][mi][1], src0);
            unsigned e02 = (unsigned)__shfl((int)vpk[0][mi][0], src1), e03 = (unsigned)__shfl((int)vpk[0][mi][1], src1);
            unsigned f00 = (unsigned)__shfl((int)vpk[1][mi][0], src0), f01 = (unsigned)__shfl((int)vpk[1][mi][1], src0);
            unsigned f02 = (unsigned)__shfl((int)vpk[1][mi][0], src1), f03 = (unsigned)__shfl((int)vpk[1][mi][1], src1);
            uint4 u0;
            u0.x = hi ? f00 : e00; u0.y = hi ? f01 : e01; u0.z = hi ? f02 : e02; u0.w = hi ? f03 : e03;
            unsigned e10 = (unsigned)__shfl((int)vpk[2][mi][0], src0), e11 = (unsigned)__shfl((int)vpk[2][mi][1], src0);
            unsigned e12 = (unsigned)__shfl((int)vpk[2][mi][0], src1), e13 = (unsigned)__shfl((int)vpk[2][mi][1], src1);
            unsigned f10 = (unsigned)__shfl((int)vpk[3][mi][0], src0), f11 = (unsigned)__shfl((int)vpk[3][mi][1], src0);
            unsigned f12 = (unsigned)__shfl((int)vpk[3][mi][0], src1), f13 = (unsigned)__shfl((int)vpk[3][mi][1], src1);
            uint4 u1;
            u1.x = hi ? f10 : e10; u1.y = hi ? f11 : e11; u1.z = hi ? f12 : e12; u1.w = hi ? f13 : e13;
            __builtin_memcpy(&va[mi][0], &u0, 16);
            __builtin_memcpy(&va[mi][1], &u1, 16);
        }

        __syncthreads();                 // bar2: y visible (x reads all done too)

        if (p + stride < B) loadx(p + stride);   // prefetch under compute

        // scores + softmax for this wave's query tile c = w4 (own half)
        {
            const short* yb = yh + (16 * w4 + r) * XS;
            bf16x8 by[4];
            #pragma unroll
            for (int kk = 0; kk < 3; ++kk) by[kk] = *(const bf16x8*)(yb + 32 * kk + 8 * g);
            by[3] = zz;
            if (g == 0) by[3] = *(const bf16x8*)(yb + 96);

            float sc[4][4];
            #pragma unroll
            for (int mt = 0; mt < 4; ++mt) {
                f32x4 acc = {0.f, 0.f, 0.f, 0.f};
                #pragma unroll
                for (int kk = 0; kk < 4; ++kk)
                    acc = __builtin_amdgcn_mfma_f32_16x16x32_bf16(ax[mt][kk], by[kk], acc, 0, 0, 0);
                #pragma unroll
                for (int j = 0; j < 4; ++j) sc[mt][j] = acc[j];
            }
            #pragma unroll
            for (int j = 0; j < 4; ++j)
                if (48 + 4 * g + j >= HALFS) sc[3][j] = -1e30f;

            float mx = -1e30f;
            #pragma unroll
            for (int mt = 0; mt < 4; ++mt) {
                #pragma unroll
                for (int j = 0; j < 4; ++j) mx = fmaxf(mx, sc[mt][j]);
            }
            mx = fmaxf(mx, __shfl_xor(mx, 16));
            mx = fmaxf(mx, __shfl_xor(mx, 32));
            float pr[4][4];
            float sum = 0.f;
            #pragma unroll
            for (int mt = 0; mt < 4; ++mt) {
                #pragma unroll
                for (int j = 0; j < 4; ++j) { pr[mt][j] = __expf(sc[mt][j] - mx); sum += pr[mt][j]; }
            }
            sum += __shfl_xor(sum, 16);
            sum += __shfl_xor(sum, 32);
            float rs = 1.0f / sum;

            #pragma unroll
            for (int mt = 0; mt < 4; ++mt) {
                uint2 t2;
                t2.x = pk2(pr[mt][0] * rs, pr[mt][1] * rs);
                t2.y = pk2(pr[mt][2] * rs, pr[mt][3] * rs);
                *(uint2*)(Ph + (16 * w4 + r) * PS + 16 * mt + 4 * g) = t2;
            }
        }
        __syncthreads();                 // P-bar: all P rows visible

        // PV per c, stores to this group's output half
        const size_t obase = (size_t)p * (SEQ * HEAD) + (size_t)(h * HALFS) * HEAD;
        #pragma unroll
        for (int c = 0; c < 4; ++c) {
            const short* pb = Ph + (16 * c + r) * PS + 8 * g;
            bf16x8 bp0 = *(const bf16x8*)(pb);
            bf16x8 bp1 = *(const bf16x8*)(pb + 32);
            const int srow  = 16 * c + r;
            const bool valid = srow < HALFS;
            float* orow = out + obase + (size_t)srow * HEAD;
            #pragma unroll
            for (int mi = 0; mi < 3; ++mi) {
                f32x4 acc = {0.f, 0.f, 0.f, 0.f};
                acc = __builtin_amdgcn_mfma_f32_16x16x32_bf16(va[mi][0], bp0, acc, 0, 0, 0);
                acc = __builtin_amdgcn_mfma_f32_16x16x32_bf16(va[mi][1], bp1, acc, 0, 0, 0);
                if (valid) {
                    float4 st4; st4.x = acc[0]; st4.y = acc[1]; st4.z = acc[2]; st4.w = acc[3];
                    *(float4*)(orow + 16 * (w4 + 4 * mi) + 4 * g) = st4;
                }
            }
        }
        __syncthreads();                 // bar-end: y/P reads done before next stage
    }
}

extern "C" void kernel_launch(void* const* d_in, const int* in_sizes, int n_in,
                              void* d_out, int out_size, void* d_ws, size_t ws_size,
                              hipStream_t stream) {
    const float* x  = (const float*)d_in[0];
    const float* Wq = (const float*)d_in[1];
    const float* Wk = (const float*)d_in[2];
    const float* Wv = (const float*)d_in[3];
    short* ws = (short*)d_ws;                       // needs (14336+24576)*2 = 77824 B
    int B = in_sizes[0] / (SEQ * EMB);              // 8192
    int prep_elems = MT_SHORTS + HEAD * WES;
    prep<<<(prep_elems + 255) / 256, 256, 0, stream>>>(Wq, Wk, Wv, ws);
    attn_head<<<512, 512, 0, stream>>>(x, ws, (float*)d_out, B);
}